// Round 2
// baseline (208.913 us; speedup 1.0000x reference)
//
#include <hip/hip_runtime.h>
#include <math.h>

#define SS 192
#define HH 128
#define KDIM 50

// ---------------------------------------------------------------------------
// Cox-de Boor features for one scalar: o[0..7] = 8 cubic B-spline bases on
// the efficient-kan grid (12 uniform knots, spacing 0.4 on [-2.2, 2.2]),
// o[8] = silu(x). Matches the reference recursion; divisions by constant
// knot differences fold to compile-time reciprocals (<=1ulp delta).
// ---------------------------------------------------------------------------
__device__ __forceinline__ void kan_phi9(float x, float* o) {
    float g[12];
#pragma unroll
    for (int i = 0; i < 12; ++i) g[i] = (float)(i - 3) * 0.4f - 1.0f;
    float b[11];
#pragma unroll
    for (int i = 0; i < 11; ++i) b[i] = (x >= g[i] && x < g[i + 1]) ? 1.0f : 0.0f;
#pragma unroll
    for (int p = 1; p <= 3; ++p) {
#pragma unroll
        for (int i = 0; i + p < 11; ++i) {
            float l = (x - g[i]) * (1.0f / (g[i + p] - g[i]));
            float r = (g[i + p + 1] - x) * (1.0f / (g[i + p + 1] - g[i + 1]));
            b[i] = l * b[i] + r * b[i + 1];   // ascending in-place: b[i+1] still old
        }
    }
#pragma unroll
    for (int i = 0; i < 8; ++i) o[i] = b[i];
    o[8] = x / (1.0f + expf(-x));
}

// ---------------------------------------------------------------------------
// K1 (256 thr): blocks 0..143 -> U[m][i][k], Vt[m][k][j] (layer-0 of the pair
// KANs, split by concat-linearity: layer0(cat[h_i,h_j]) = U[i] + V[j]).
// 4 rows/block, h-reduction split across 2 thread groups. Block 144 computes
// the modal-fusion softmax weights wts[3].
// ---------------------------------------------------------------------------
__global__ __launch_bounds__(256) void k1_stage(
    const float* __restrict__ x, const float* __restrict__ y, const float* __restrict__ tg,
    const float* __restrict__ xb0, const float* __restrict__ xs0,
    const float* __restrict__ yb0, const float* __restrict__ ys0,
    const float* __restrict__ tb0, const float* __restrict__ ts0,
    const float* __restrict__ fb0, const float* __restrict__ fs0,
    const float* __restrict__ fb1, const float* __restrict__ fs1,
    float* __restrict__ U, float* __restrict__ Vt, float* __restrict__ wts)
{
    __shared__ float lds[7168];
    const int tid = threadIdx.x;
    const int bid = blockIdx.x;
    const int lane = tid & 63, wv = tid >> 6;

    if (bid < 144) {
        const int m  = bid / 48;
        const int i0 = (bid % 48) * 4;
        const float* in = (m == 0) ? x   : (m == 1) ? y   : tg;
        const float* b0 = (m == 0) ? xb0 : (m == 1) ? yb0 : tb0;
        const float* s0 = (m == 0) ? xs0 : (m == 1) ? ys0 : ts0;

        // stage features: lds[r*1536 + h*12 + c], c 0..7 bases, 8 silu
        for (int idx = tid; idx < 512; idx += 256) {
            const int r = idx >> 7, h = idx & 127;
            float ph[9];
            kan_phi9(in[(i0 + r) * HH + h], ph);
#pragma unroll
            for (int c = 0; c < 9; ++c) lds[r * 1536 + h * 12 + c] = ph[c];
        }
        __syncthreads();

        const int k    = tid & 63;          // spline-layer output index
        const int half = (tid >> 6) & 1;    // 0 -> U (row half), 1 -> V (col half)
        const int hh   = tid >> 7;          // h-range split
        float* part = lds + 6144;           // [hh][half][64][4]
        if (k < KDIM) {
            const float* bw = b0 + k * 256 + half * 128 + hh * 64;
            const float* sw = s0 + (size_t)(k * 256 + half * 128 + hh * 64) * 8;
            float a0 = 0.f, a1 = 0.f, a2 = 0.f, a3 = 0.f;
            for (int hl = 0; hl < 64; ++hl) {
                const int h = hh * 64 + hl;
                const float  wbv = bw[hl];
                const float* swh = sw + hl * 8;
                const float* f0 = lds + 0 * 1536 + h * 12;   // wave-uniform -> LDS broadcast
                const float* f1 = lds + 1 * 1536 + h * 12;
                const float* f2 = lds + 2 * 1536 + h * 12;
                const float* f3 = lds + 3 * 1536 + h * 12;
                a0 += f0[8] * wbv; a1 += f1[8] * wbv; a2 += f2[8] * wbv; a3 += f3[8] * wbv;
#pragma unroll
                for (int n = 0; n < 8; ++n) {
                    const float wv2 = swh[n];
                    a0 += f0[n] * wv2; a1 += f1[n] * wv2; a2 += f2[n] * wv2; a3 += f3[n] * wv2;
                }
            }
            const int pb = ((hh * 2 + half) * 64 + k) * 4;
            part[pb + 0] = a0; part[pb + 1] = a1; part[pb + 2] = a2; part[pb + 3] = a3;
        }
        __syncthreads();
        if (hh == 0 && k < KDIM) {
#pragma unroll
            for (int r = 0; r < 4; ++r) {
                const float s = part[((0 * 2 + half) * 64 + k) * 4 + r]
                              + part[((1 * 2 + half) * 64 + k) * 4 + r];
                if (half == 0) U[(m * SS + i0 + r) * KDIM + k] = s;
                else           Vt[(m * KDIM + k) * SS + i0 + r] = s;
            }
        }
    } else {
        // ---- modal fusion weights (depend only on raw inputs) ----
        float* mf     = lds;          // 384
        float* zpartw = lds + 384;    // 50*4 = 200
        float* z      = lds + 584;    // 50
        float* part3  = lds + 634;    // 150

        for (int col = tid; col < 384; col += 256) {
            const int mm = col >> 7, cc = col & 127;
            const float* in = (mm == 0) ? x : (mm == 1) ? y : tg;
            float s = 0.f;
            for (int r = 0; r < SS; ++r) s += in[r * HH + cc];
            mf[col] = s / 192.0f;
        }
        __syncthreads();
        // layer0: z[k] = sum_f phi(mf[f]) . w[k][f]; f-parallel, wave-reduced
        float zp[KDIM];
#pragma unroll
        for (int k = 0; k < KDIM; ++k) zp[k] = 0.f;
        for (int f = tid; f < 384; f += 256) {
            float ph[9];
            kan_phi9(mf[f], ph);
#pragma unroll
            for (int k = 0; k < KDIM; ++k) {
                float a = ph[8] * fb0[k * 384 + f];
                const float* sw = fs0 + (size_t)(k * 384 + f) * 8;
#pragma unroll
                for (int n = 0; n < 8; ++n) a += ph[n] * sw[n];
                zp[k] += a;
            }
        }
#pragma unroll
        for (int k = 0; k < KDIM; ++k) {
            float v = zp[k];
#pragma unroll
            for (int o = 32; o > 0; o >>= 1) v += __shfl_xor(v, o);
            if (lane == 0) zpartw[k * 4 + wv] = v;
        }
        __syncthreads();
        if (tid < KDIM)
            z[tid] = zpartw[tid * 4 + 0] + zpartw[tid * 4 + 1]
                   + zpartw[tid * 4 + 2] + zpartw[tid * 4 + 3];
        __syncthreads();
        if (tid < KDIM) {   // layer1 partials, k-parallel
            float ph[9];
            kan_phi9(z[tid], ph);
#pragma unroll
            for (int oo = 0; oo < 3; ++oo) {
                float a = ph[8] * fb1[oo * KDIM + tid];
                const float* sw = fs1 + (oo * KDIM + tid) * 8;
#pragma unroll
                for (int n = 0; n < 8; ++n) a += ph[n] * sw[n];
                part3[oo * KDIM + tid] = a;
            }
        }
        __syncthreads();
        if (tid == 0) {
            float o0 = 0.f, o1 = 0.f, o2 = 0.f;
            for (int k = 0; k < KDIM; ++k) {
                o0 += part3[k]; o1 += part3[KDIM + k]; o2 += part3[2 * KDIM + k];
            }
            const float M  = fmaxf(o0, fmaxf(o1, o2));
            const float e0 = expf(o0 - M), e1 = expf(o1 - M), e2 = expf(o2 - M);
            const float s  = e0 + e1 + e2;
            wts[0] = e0 / s; wts[1] = e1 / s; wts[2] = e2 / s;
        }
    }
}

// ---------------------------------------------------------------------------
// K2 (576 thr, one block per row i): per-pair layer-1 KAN on z = U[i]+V[j]
// (closed-form uniform cubic B-spline, 4 nonzero bases vs zero-padded s1 rows
// in LDS). Thread = (modality m, column j). Then fusion + bias, row softmax,
// att @ target (4-way row-chunk parallel).
// ---------------------------------------------------------------------------
__global__ __launch_bounds__(576) void k2_att(
    const float* __restrict__ tg,
    const float* __restrict__ xb1, const float* __restrict__ xs1,
    const float* __restrict__ yb1, const float* __restrict__ ys1,
    const float* __restrict__ tb1, const float* __restrict__ ts1,
    const float* __restrict__ bias,
    const float* __restrict__ U, const float* __restrict__ Vt,
    const float* __restrict__ wts, float* __restrict__ out)
{
    __shared__ float spad[3 * KDIM * 14];   // s1 rows, 3 zeros padding each side
    __shared__ float Uls[3 * KDIM];
    __shared__ float b1ls[3 * KDIM];
    __shared__ float smpart[576];
    __shared__ float att[SS];
    __shared__ float opart[512];
    __shared__ float red[20];
    __shared__ float wb[4];
    const int tid = threadIdx.x;
    const int i   = blockIdx.x;
    const int lane = tid & 63, wv = tid >> 6;

    for (int idx = tid; idx < 3 * KDIM * 14; idx += 576) {
        const int m = idx / (KDIM * 14);
        const int r = idx % (KDIM * 14);
        const int k = r / 14, c = r % 14;
        const float* s1 = (m == 0) ? xs1 : (m == 1) ? ys1 : ts1;
        spad[idx] = (c >= 3 && c < 11) ? s1[k * 8 + (c - 3)] : 0.f;
    }
    if (tid < 3 * KDIM) {
        const int m = tid / KDIM, k = tid % KDIM;
        const float* b1 = (m == 0) ? xb1 : (m == 1) ? yb1 : tb1;
        b1ls[tid] = b1[k];
        Uls[tid]  = U[(m * SS + i) * KDIM + k];
    }
    if (tid < 3)  wb[tid] = wts[tid];
    if (tid == 3) wb[3] = bias[0];
    __syncthreads();

    {   // phase 1: sm(m, j) for this thread's (m, j)
        const int m = tid / 192, j = tid % 192;
        const float* vcol = Vt + m * KDIM * SS + j;
        const float* spm  = spad + m * KDIM * 14;
        const float* Um   = Uls + m * KDIM;
        const float* bm   = b1ls + m * KDIM;
        float sm = 0.f;
        for (int k = 0; k < KDIM; ++k) {
            const float zv  = Um[k] + vcol[k * SS];       // coalesced across j
            const float sig = 1.0f / (1.0f + expf(-zv));
            sm += zv * sig * bm[k];
            // closed-form uniform cubic B-spline: cell c, frac u, 4 weights
            float t = (zv + 2.2f) * 2.5f;
            const bool inr = (t >= 0.0f) && (t < 11.0f);
            t = inr ? t : 0.0f;
            const int   c  = (int)t;
            const float u  = t - (float)c;
            const float u2 = u * u, u3 = u2 * u;
            const float wA = (1.0f/6.0f) * (1.0f - 3.0f*u + 3.0f*u2 - u3);
            const float wB = (1.0f/6.0f) * (3.0f*u3 - 6.0f*u2 + 4.0f);
            const float wC = (1.0f/6.0f) * (-3.0f*u3 + 3.0f*u2 + 3.0f*u + 1.0f);
            const float wD = (1.0f/6.0f) * u3;
            const float* sp = spm + k * 14 + c;           // sp[0] == s1[c-3] (padded)
            const float spl = wA*sp[0] + wB*sp[1] + wC*sp[2] + wD*sp[3];
            sm += inr ? spl : 0.0f;
        }
        smpart[tid] = wb[m] * sm;
    }
    __syncthreads();

    // phase 2: fuse + row softmax over 192 columns (threads 0..191, 3 waves)
    float f = 0.f;
    if (tid < SS) f = wb[3] + smpart[tid] + smpart[tid + 192] + smpart[tid + 384];
    float mx = f;
#pragma unroll
    for (int o = 32; o > 0; o >>= 1) mx = fmaxf(mx, __shfl_xor(mx, o));
    if (lane == 0) red[wv] = mx;
    __syncthreads();
    mx = fmaxf(red[0], fmaxf(red[1], red[2]));
    const float p = (tid < SS) ? expf(f - mx) : 0.f;
    float sum = p;
#pragma unroll
    for (int o = 32; o > 0; o >>= 1) sum += __shfl_xor(sum, o);
    if (lane == 0) red[10 + wv] = sum;
    __syncthreads();
    sum = red[10] + red[11] + red[12];
    if (tid < SS) att[tid] = p / sum;
    __syncthreads();

    // phase 3: out[i][:] = att @ target, 4 row-chunks of 48 in parallel
    if (tid < 512) {
        const int col = tid & 127, ch = tid >> 7;
        float acc = 0.f;
        for (int jj = ch * 48; jj < ch * 48 + 48; ++jj)
            acc += att[jj] * tg[jj * HH + col];
        opart[tid] = acc;
    }
    __syncthreads();
    if (tid < HH)
        out[i * HH + tid] = opart[tid] + opart[tid + 128] + opart[tid + 256] + opart[tid + 384];
}

// ---------------------------------------------------------------------------
// K3/K4: y = relu(kan_linear(in, bw, sw)) for (192,128)->(192,128).
// 2 rows/block, 256 threads: o = tid&127, h-split across tid>>7.
// ---------------------------------------------------------------------------
__global__ __launch_bounds__(256) void k3_kanlin_relu(
    const float* __restrict__ in, const float* __restrict__ bw, const float* __restrict__ sw,
    float* __restrict__ out)
{
    __shared__ float lds[3584];            // feat 2*1536, part 512 @3072
    const int tid = threadIdx.x;
    const int i0  = blockIdx.x * 2;
    {
        const int r = tid >> 7, h = tid & 127;
        float ph[9];
        kan_phi9(in[(i0 + r) * HH + h], ph);
#pragma unroll
        for (int c = 0; c < 9; ++c) lds[r * 1536 + h * 12 + c] = ph[c];
    }
    __syncthreads();
    const int o  = tid & 127;
    const int hh = tid >> 7;
    const float* br = bw + o * HH + hh * 64;
    const float* sr = sw + (size_t)(o * HH + hh * 64) * 8;
    float a0 = 0.f, a1 = 0.f;
    for (int hl = 0; hl < 64; ++hl) {
        const int h = hh * 64 + hl;
        const float  wbv = br[hl];
        const float* swh = sr + hl * 8;
        const float* f0 = lds + 0 * 1536 + h * 12;        // wave-uniform -> broadcast
        const float* f1 = lds + 1 * 1536 + h * 12;
        a0 += f0[8] * wbv; a1 += f1[8] * wbv;
#pragma unroll
        for (int n = 0; n < 8; ++n) {
            const float wv = swh[n];
            a0 += f0[n] * wv; a1 += f1[n] * wv;
        }
    }
    float* part = lds + 3072;              // [hh][o][r]
    part[((hh << 7) | o) * 2 + 0] = a0;
    part[((hh << 7) | o) * 2 + 1] = a1;
    __syncthreads();
    if (hh == 0) {
#pragma unroll
        for (int r = 0; r < 2; ++r) {
            const float s = part[o * 2 + r] + part[(128 + o) * 2 + r];
            out[(i0 + r) * HH + o] = fmaxf(s, 0.f);
        }
    }
}

// ---------------------------------------------------------------------------
extern "C" void kernel_launch(void* const* d_in, const int* in_sizes, int n_in,
                              void* d_out, int out_size, void* d_ws, size_t ws_size,
                              hipStream_t stream) {
    const float* x    = (const float*)d_in[0];
    const float* y    = (const float*)d_in[1];
    const float* tg   = (const float*)d_in[2];
    const float* bias = (const float*)d_in[3];
    const float* xb0  = (const float*)d_in[4];
    const float* xs0  = (const float*)d_in[5];
    const float* xb1  = (const float*)d_in[6];
    const float* xs1  = (const float*)d_in[7];
    const float* yb0  = (const float*)d_in[8];
    const float* ys0  = (const float*)d_in[9];
    const float* yb1  = (const float*)d_in[10];
    const float* ys1  = (const float*)d_in[11];
    const float* tb0  = (const float*)d_in[12];
    const float* ts0  = (const float*)d_in[13];
    const float* tb1  = (const float*)d_in[14];
    const float* ts1  = (const float*)d_in[15];
    const float* fb0  = (const float*)d_in[16];
    const float* fs0  = (const float*)d_in[17];
    const float* fb1  = (const float*)d_in[18];
    const float* fs1  = (const float*)d_in[19];
    const float* l1b  = (const float*)d_in[20];
    const float* l1s  = (const float*)d_in[21];
    const float* l2b  = (const float*)d_in[22];
    const float* l2s  = (const float*)d_in[23];

    float* ws   = (float*)d_ws;
    float* U    = ws;             // 3*192*50 = 28800
    float* Vt   = ws + 28800;     // 28800
    float* wts  = ws + 57600;     // 3 (padded to 64)
    float* tgt  = ws + 57664;     // 24576
    float* y1   = ws + 82240;     // 24576  (total ~427 KB)
    float* outp = (float*)d_out;

    k1_stage<<<145, 256, 0, stream>>>(x, y, tg, xb0, xs0, yb0, ys0, tb0, ts0,
                                      fb0, fs0, fb1, fs1, U, Vt, wts);
    k2_att<<<SS, 576, 0, stream>>>(tg, xb1, xs1, yb1, ys1, tb1, ts1, bias,
                                   U, Vt, wts, tgt);
    k3_kanlin_relu<<<96, 256, 0, stream>>>(tgt, l1b, l1s, y1);
    k3_kanlin_relu<<<96, 256, 0, stream>>>(y1, l2b, l2s, outp);
}

// Round 3
// 202.921 us; speedup vs baseline: 1.0295x; 1.0295x over previous
//
#include <hip/hip_runtime.h>
#include <math.h>

#define SS 192
#define HH 128
#define KDIM 50

// ---------------------------------------------------------------------------
// Cox-de Boor features for one scalar: o[0..7] = 8 cubic B-spline bases on
// the efficient-kan grid (12 uniform knots, spacing 0.4 on [-2.2, 2.2]),
// o[8] = silu(x). Matches the reference recursion; divisions by constant
// knot differences fold to compile-time reciprocals (<=1ulp delta).
// ---------------------------------------------------------------------------
__device__ __forceinline__ void kan_phi9(float x, float* o) {
    float g[12];
#pragma unroll
    for (int i = 0; i < 12; ++i) g[i] = (float)(i - 3) * 0.4f - 1.0f;
    float b[11];
#pragma unroll
    for (int i = 0; i < 11; ++i) b[i] = (x >= g[i] && x < g[i + 1]) ? 1.0f : 0.0f;
#pragma unroll
    for (int p = 1; p <= 3; ++p) {
#pragma unroll
        for (int i = 0; i + p < 11; ++i) {
            float l = (x - g[i]) * (1.0f / (g[i + p] - g[i]));
            float r = (g[i + p + 1] - x) * (1.0f / (g[i + p + 1] - g[i + 1]));
            b[i] = l * b[i] + r * b[i + 1];   // ascending in-place: b[i+1] still old
        }
    }
#pragma unroll
    for (int i = 0; i < 8; ++i) o[i] = b[i];
    o[8] = x / (1.0f + expf(-x));
}

// ---------------------------------------------------------------------------
// K0: weight re-layout so compute kernels load lane-coalesced.
//   wt[m][half][h][n][kk] (kk = output k, padded 50->64, zeros beyond):
//       n<8 -> s0_m[k][half*128+h][n];  n==8 -> b0_m[k][half*128+h]
//   lt[h][n][o]  (o = output, 128 wide):
//       n<8 -> l?s[o][h][n];            n==8 -> l?b[o][h]
// Writes coalesced (linear gid); scattered reads are L2-absorbed.
// ---------------------------------------------------------------------------
#define WT_ELEMS   442368                 // 3*2*128*9*64
#define LT_ELEMS   147456                 // 128*9*128
__global__ __launch_bounds__(256) void k0_prep(
    const float* __restrict__ xb0, const float* __restrict__ xs0,
    const float* __restrict__ yb0, const float* __restrict__ ys0,
    const float* __restrict__ tb0, const float* __restrict__ ts0,
    const float* __restrict__ l1b, const float* __restrict__ l1s,
    const float* __restrict__ l2b, const float* __restrict__ l2s,
    float* __restrict__ wt, float* __restrict__ lt1, float* __restrict__ lt2)
{
    const int gid = blockIdx.x * 256 + threadIdx.x;
    if (gid < WT_ELEMS) {
        const int kk = gid & 63;
        int t = gid >> 6;
        const int n = t % 9; t /= 9;
        const int h = t & 127; t >>= 7;
        const int half = t & 1;
        const int m = t >> 1;
        const float* b0 = (m == 0) ? xb0 : (m == 1) ? yb0 : tb0;
        const float* s0 = (m == 0) ? xs0 : (m == 1) ? ys0 : ts0;
        float v = 0.f;
        if (kk < KDIM) {
            const int col = half * 128 + h;
            v = (n < 8) ? s0[(kk * 256 + col) * 8 + n] : b0[kk * 256 + col];
        }
        wt[gid] = v;
    } else {
        int idx = gid - WT_ELEMS;
        const int which = idx >= LT_ELEMS;
        if (which) idx -= LT_ELEMS;
        const float* ls = which ? l2s : l1s;
        const float* lb = which ? l2b : l1b;
        const int o = idx & 127;
        const int t = idx >> 7;
        const int n = t % 9;
        const int h = t / 9;
        const float v = (n < 8) ? ls[(o * 128 + h) * 8 + n] : lb[o * 128 + h];
        (which ? lt2 : lt1)[idx] = v;
    }
}

// ---------------------------------------------------------------------------
// K1 (256 thr): blocks 0..143 -> U[m][i][k], Vt[m][k][j] (layer-0 of the pair
// KANs, split by concat-linearity: layer0(cat[h_i,h_j]) = U[i] + V[j]).
// 4 rows/block; wave = (hh, half), lane = kk -> all weight loads coalesced,
// phi reads wave-uniform LDS broadcasts. Block 144: fusion softmax weights.
// ---------------------------------------------------------------------------
__global__ __launch_bounds__(256) void k1_stage(
    const float* __restrict__ x, const float* __restrict__ y, const float* __restrict__ tg,
    const float* __restrict__ wt,
    const float* __restrict__ fb0, const float* __restrict__ fs0,
    const float* __restrict__ fb1, const float* __restrict__ fs1,
    float* __restrict__ U, float* __restrict__ Vt, float* __restrict__ wts)
{
    __shared__ float lds[7168];
    const int tid = threadIdx.x;
    const int bid = blockIdx.x;
    const int lane = tid & 63, wv = tid >> 6;

    if (bid < 144) {
        const int m  = bid / 48;
        const int i0 = (bid % 48) * 4;
        const float* in = (m == 0) ? x : (m == 1) ? y : tg;

        // stage features: lds[r*1536 + h*12 + c], c: 0..7 bases, 8 silu
        for (int idx = tid; idx < 512; idx += 256) {
            const int r = idx >> 7, h = idx & 127;
            float ph[9];
            kan_phi9(in[(i0 + r) * HH + h], ph);
#pragma unroll
            for (int c = 0; c < 9; ++c) lds[r * 1536 + h * 12 + c] = ph[c];
        }
        __syncthreads();

        const int kk   = tid & 63;          // output k (lane -> coalesced loads)
        const int half = (tid >> 6) & 1;    // 0 -> U (row half), 1 -> V (col half)
        const int hh   = tid >> 7;          // h-range split
        const float* wp = wt + ((size_t)((m * 2 + half) * 128 + hh * 64) * 9) * 64 + kk;
        float a0 = 0.f, a1 = 0.f, a2 = 0.f, a3 = 0.f;
        for (int hl = 0; hl < 64; ++hl) {
            const float* f0 = lds + (hh * 64 + hl) * 12;    // wave-uniform -> broadcast
            const float* f1 = f0 + 1536;
            const float* f2 = f0 + 3072;
            const float* f3 = f0 + 4608;
            const float* wrow = wp + hl * 576;
#pragma unroll
            for (int n = 0; n < 9; ++n) {
                const float w = wrow[n * 64];               // 256B coalesced
                a0 += f0[n] * w; a1 += f1[n] * w; a2 += f2[n] * w; a3 += f3[n] * w;
            }
        }
        float* part = lds + 6144;           // [hh][half][64][4]
        const int pb = ((hh * 2 + half) * 64 + kk) * 4;
        part[pb + 0] = a0; part[pb + 1] = a1; part[pb + 2] = a2; part[pb + 3] = a3;
        __syncthreads();
        if (hh == 0 && kk < KDIM) {
#pragma unroll
            for (int r = 0; r < 4; ++r) {
                const float s = part[(half * 64 + kk) * 4 + r]
                              + part[((2 + half) * 64 + kk) * 4 + r];
                if (half == 0) U[(m * SS + i0 + r) * KDIM + kk] = s;
                else           Vt[(m * KDIM + kk) * SS + i0 + r] = s;
            }
        }
    } else {
        // ---- modal fusion weights (depend only on raw inputs) ----
        float* mf     = lds;          // 384
        float* zpartw = lds + 384;    // 50*4
        float* z      = lds + 584;    // 50
        float* part3  = lds + 634;    // 150

        for (int col = tid; col < 384; col += 256) {
            const int mm = col >> 7, cc = col & 127;
            const float* in = (mm == 0) ? x : (mm == 1) ? y : tg;
            float s = 0.f;
            for (int r = 0; r < SS; ++r) s += in[r * HH + cc];
            mf[col] = s / 192.0f;
        }
        __syncthreads();
        float zp[KDIM];
#pragma unroll
        for (int k = 0; k < KDIM; ++k) zp[k] = 0.f;
        for (int f = tid; f < 384; f += 256) {
            float ph[9];
            kan_phi9(mf[f], ph);
#pragma unroll
            for (int k = 0; k < KDIM; ++k) {
                float a = ph[8] * fb0[k * 384 + f];
                const float* sw = fs0 + (size_t)(k * 384 + f) * 8;
#pragma unroll
                for (int n = 0; n < 8; ++n) a += ph[n] * sw[n];
                zp[k] += a;
            }
        }
#pragma unroll
        for (int k = 0; k < KDIM; ++k) {
            float v = zp[k];
#pragma unroll
            for (int o = 32; o > 0; o >>= 1) v += __shfl_xor(v, o);
            if (lane == 0) zpartw[k * 4 + wv] = v;
        }
        __syncthreads();
        if (tid < KDIM)
            z[tid] = zpartw[tid * 4 + 0] + zpartw[tid * 4 + 1]
                   + zpartw[tid * 4 + 2] + zpartw[tid * 4 + 3];
        __syncthreads();
        if (tid < KDIM) {
            float ph[9];
            kan_phi9(z[tid], ph);
#pragma unroll
            for (int oo = 0; oo < 3; ++oo) {
                float a = ph[8] * fb1[oo * KDIM + tid];
                const float* sw = fs1 + (oo * KDIM + tid) * 8;
#pragma unroll
                for (int n = 0; n < 8; ++n) a += ph[n] * sw[n];
                part3[oo * KDIM + tid] = a;
            }
        }
        __syncthreads();
        if (tid == 0) {
            float o0 = 0.f, o1 = 0.f, o2 = 0.f;
            for (int k = 0; k < KDIM; ++k) {
                o0 += part3[k]; o1 += part3[KDIM + k]; o2 += part3[2 * KDIM + k];
            }
            const float M  = fmaxf(o0, fmaxf(o1, o2));
            const float e0 = expf(o0 - M), e1 = expf(o1 - M), e2 = expf(o2 - M);
            const float s  = e0 + e1 + e2;
            wts[0] = e0 / s; wts[1] = e1 / s; wts[2] = e2 / s;
        }
    }
}

// ---------------------------------------------------------------------------
// K2 (576 thr, one block per row i): per-pair layer-1 KAN on z = U[i]+V[j]
// (closed-form uniform cubic B-spline vs zero-padded s1 rows in LDS).
// Thread = (modality m, column j). Fusion + bias, row softmax, att @ target.
// ---------------------------------------------------------------------------
__global__ __launch_bounds__(576) void k2_att(
    const float* __restrict__ tg,
    const float* __restrict__ xb1, const float* __restrict__ xs1,
    const float* __restrict__ yb1, const float* __restrict__ ys1,
    const float* __restrict__ tb1, const float* __restrict__ ts1,
    const float* __restrict__ bias,
    const float* __restrict__ U, const float* __restrict__ Vt,
    const float* __restrict__ wts, float* __restrict__ out)
{
    __shared__ float spad[3 * KDIM * 14];   // s1 rows, 3 zeros padding each side
    __shared__ float Uls[3 * KDIM];
    __shared__ float b1ls[3 * KDIM];
    __shared__ float smpart[576];
    __shared__ float att[SS];
    __shared__ float opart[512];
    __shared__ float red[20];
    __shared__ float wb[4];
    const int tid = threadIdx.x;
    const int i   = blockIdx.x;
    const int lane = tid & 63, wv = tid >> 6;

    for (int idx = tid; idx < 3 * KDIM * 14; idx += 576) {
        const int m = idx / (KDIM * 14);
        const int r = idx % (KDIM * 14);
        const int k = r / 14, c = r % 14;
        const float* s1 = (m == 0) ? xs1 : (m == 1) ? ys1 : ts1;
        spad[idx] = (c >= 3 && c < 11) ? s1[k * 8 + (c - 3)] : 0.f;
    }
    if (tid < 3 * KDIM) {
        const int m = tid / KDIM, k = tid % KDIM;
        const float* b1 = (m == 0) ? xb1 : (m == 1) ? yb1 : tb1;
        b1ls[tid] = b1[k];
        Uls[tid]  = U[(m * SS + i) * KDIM + k];
    }
    if (tid < 3)  wb[tid] = wts[tid];
    if (tid == 3) wb[3] = bias[0];
    __syncthreads();

    {   // phase 1: sm(m, j)
        const int m = tid / 192, j = tid % 192;
        const float* vcol = Vt + m * KDIM * SS + j;
        const float* spm  = spad + m * KDIM * 14;
        const float* Um   = Uls + m * KDIM;
        const float* bm   = b1ls + m * KDIM;
        float sm = 0.f;
        for (int k = 0; k < KDIM; ++k) {
            const float zv  = Um[k] + vcol[k * SS];       // coalesced across j
            const float sig = 1.0f / (1.0f + expf(-zv));
            sm += zv * sig * bm[k];
            float t = (zv + 2.2f) * 2.5f;
            const bool inr = (t >= 0.0f) && (t < 11.0f);
            t = inr ? t : 0.0f;
            const int   c  = (int)t;
            const float u  = t - (float)c;
            const float u2 = u * u, u3 = u2 * u;
            const float wA = (1.0f/6.0f) * (1.0f - 3.0f*u + 3.0f*u2 - u3);
            const float wB = (1.0f/6.0f) * (3.0f*u3 - 6.0f*u2 + 4.0f);
            const float wC = (1.0f/6.0f) * (-3.0f*u3 + 3.0f*u2 + 3.0f*u + 1.0f);
            const float wD = (1.0f/6.0f) * u3;
            const float* sp = spm + k * 14 + c;           // sp[0] == s1[c-3] (padded)
            const float spl = wA*sp[0] + wB*sp[1] + wC*sp[2] + wD*sp[3];
            sm += inr ? spl : 0.0f;
        }
        smpart[tid] = wb[m] * sm;
    }
    __syncthreads();

    // phase 2: fuse + row softmax over 192 columns (threads 0..191)
    float f = 0.f;
    if (tid < SS) f = wb[3] + smpart[tid] + smpart[tid + 192] + smpart[tid + 384];
    float mx = f;
#pragma unroll
    for (int o = 32; o > 0; o >>= 1) mx = fmaxf(mx, __shfl_xor(mx, o));
    if (lane == 0) red[wv] = mx;
    __syncthreads();
    mx = fmaxf(red[0], fmaxf(red[1], red[2]));
    const float p = (tid < SS) ? expf(f - mx) : 0.f;
    float sum = p;
#pragma unroll
    for (int o = 32; o > 0; o >>= 1) sum += __shfl_xor(sum, o);
    if (lane == 0) red[10 + wv] = sum;
    __syncthreads();
    sum = red[10] + red[11] + red[12];
    if (tid < SS) att[tid] = p / sum;
    __syncthreads();

    // phase 3: out[i][:] = att @ target, 4 row-chunks of 48 in parallel
    if (tid < 512) {
        const int col = tid & 127, ch = tid >> 7;
        float acc = 0.f;
        for (int jj = ch * 48; jj < ch * 48 + 48; ++jj)
            acc += att[jj] * tg[jj * HH + col];
        opart[tid] = acc;
    }
    __syncthreads();
    if (tid < HH)
        out[i * HH + tid] = opart[tid] + opart[tid + 128] + opart[tid + 256] + opart[tid + 384];
}

// ---------------------------------------------------------------------------
// K3/K4: y = relu(kan_linear(in, lt)) for (192,128)->(192,128), lt pre-
// transposed to [h][n][o]. 2 rows/block, 256 threads: o = tid&127 (lane ->
// coalesced weight loads), h-split across tid>>7, phi broadcast from LDS.
// ---------------------------------------------------------------------------
__global__ __launch_bounds__(256) void k3_kanlin_relu(
    const float* __restrict__ in, const float* __restrict__ lt,
    float* __restrict__ out)
{
    __shared__ float lds[3584];            // feat 2*1536, part 512 @3072
    const int tid = threadIdx.x;
    const int i0  = blockIdx.x * 2;
    {
        const int r = tid >> 7, h = tid & 127;
        float ph[9];
        kan_phi9(in[(i0 + r) * HH + h], ph);
#pragma unroll
        for (int c = 0; c < 9; ++c) lds[r * 1536 + h * 12 + c] = ph[c];
    }
    __syncthreads();
    const int o  = tid & 127;
    const int hh = tid >> 7;
    const float* wp = lt + ((size_t)(hh * 64) * 9) * 128 + o;
    float a0 = 0.f, a1 = 0.f;
    for (int hl = 0; hl < 64; ++hl) {
        const float* f0 = lds + (hh * 64 + hl) * 12;      // wave-uniform -> broadcast
        const float* f1 = f0 + 1536;
        const float* wrow = wp + hl * 1152;
#pragma unroll
        for (int n = 0; n < 9; ++n) {
            const float w = wrow[n * 128];                // coalesced
            a0 += f0[n] * w; a1 += f1[n] * w;
        }
    }
    float* part = lds + 3072;              // [hh][o][r]
    part[((hh << 7) | o) * 2 + 0] = a0;
    part[((hh << 7) | o) * 2 + 1] = a1;
    __syncthreads();
    if (hh == 0) {
#pragma unroll
        for (int r = 0; r < 2; ++r) {
            const float s = part[o * 2 + r] + part[(128 + o) * 2 + r];
            out[(i0 + r) * HH + o] = fmaxf(s, 0.f);
        }
    }
}

// ---------------------------------------------------------------------------
extern "C" void kernel_launch(void* const* d_in, const int* in_sizes, int n_in,
                              void* d_out, int out_size, void* d_ws, size_t ws_size,
                              hipStream_t stream) {
    const float* x    = (const float*)d_in[0];
    const float* y    = (const float*)d_in[1];
    const float* tg   = (const float*)d_in[2];
    const float* bias = (const float*)d_in[3];
    const float* xb0  = (const float*)d_in[4];
    const float* xs0  = (const float*)d_in[5];
    const float* xb1  = (const float*)d_in[6];
    const float* xs1  = (const float*)d_in[7];
    const float* yb0  = (const float*)d_in[8];
    const float* ys0  = (const float*)d_in[9];
    const float* yb1  = (const float*)d_in[10];
    const float* ys1  = (const float*)d_in[11];
    const float* tb0  = (const float*)d_in[12];
    const float* ts0  = (const float*)d_in[13];
    const float* tb1  = (const float*)d_in[14];
    const float* ts1  = (const float*)d_in[15];
    const float* fb0  = (const float*)d_in[16];
    const float* fs0  = (const float*)d_in[17];
    const float* fb1  = (const float*)d_in[18];
    const float* fs1  = (const float*)d_in[19];
    const float* l1b  = (const float*)d_in[20];
    const float* l1s  = (const float*)d_in[21];
    const float* l2b  = (const float*)d_in[22];
    const float* l2s  = (const float*)d_in[23];

    float* ws   = (float*)d_ws;
    float* wt   = ws;                       // 442368
    float* lt1  = ws + WT_ELEMS;            // 147456
    float* lt2  = lt1 + LT_ELEMS;           // 147456
    float* U    = lt2 + LT_ELEMS;           // 28800
    float* Vt   = U + 28800;                // 28800
    float* wts  = Vt + 28800;               // 64
    float* tgt  = wts + 64;                 // 24576
    float* y1   = tgt + 24576;              // 24576  (total ~3.4 MB)
    float* outp = (float*)d_out;

    k0_prep<<<2880, 256, 0, stream>>>(xb0, xs0, yb0, ys0, tb0, ts0,
                                      l1b, l1s, l2b, l2s, wt, lt1, lt2);
    k1_stage<<<145, 256, 0, stream>>>(x, y, tg, wt, fb0, fs0, fb1, fs1, U, Vt, wts);
    k2_att<<<SS, 576, 0, stream>>>(tg, xb1, xs1, yb1, ys1, tb1, ts1, bias,
                                   U, Vt, wts, tgt);
    k3_kanlin_relu<<<96, 256, 0, stream>>>(tgt, lt1, y1);
    k3_kanlin_relu<<<96, 256, 0, stream>>>(y1, lt2, outp);
}

// Round 5
// 174.258 us; speedup vs baseline: 1.1989x; 1.1645x over previous
//
#include <hip/hip_runtime.h>
#include <math.h>

#define SS 192
#define HH 128
#define KDIM 50

#define WT_ELEMS   442368                 // 3*2*128*9*64   wt[m][half][h][n][kk]
#define LT_ELEMS   147456                 // 128*9*128      lt[h][n][o]
#define FT_ELEMS   221184                 // 384*9*64       ft[f][n][kk]

// ---------------------------------------------------------------------------
// Cox-de Boor features for one scalar: o[0..7] = 8 cubic B-spline bases on
// the efficient-kan grid (12 uniform knots, spacing 0.4 on [-2.2, 2.2]),
// o[8] = silu(x). Matches the reference recursion; divisions by constant
// knot differences fold to compile-time reciprocals (<=1ulp delta).
// ---------------------------------------------------------------------------
__device__ __forceinline__ void kan_phi9(float x, float* o) {
    float g[12];
#pragma unroll
    for (int i = 0; i < 12; ++i) g[i] = (float)(i - 3) * 0.4f - 1.0f;
    float b[11];
#pragma unroll
    for (int i = 0; i < 11; ++i) b[i] = (x >= g[i] && x < g[i + 1]) ? 1.0f : 0.0f;
#pragma unroll
    for (int p = 1; p <= 3; ++p) {
#pragma unroll
        for (int i = 0; i + p < 11; ++i) {
            float l = (x - g[i]) * (1.0f / (g[i + p] - g[i]));
            float r = (g[i + p + 1] - x) * (1.0f / (g[i + p + 1] - g[i + 1]));
            b[i] = l * b[i] + r * b[i + 1];   // ascending in-place: b[i+1] still old
        }
    }
#pragma unroll
    for (int i = 0; i < 8; ++i) o[i] = b[i];
    o[8] = x / (1.0f + expf(-x));
}

// ---------------------------------------------------------------------------
// K0: weight re-layouts (lane-coalesced for the consumers). kk padded 50->64.
//   wt[m][half][h][n][kk], lt[h][n][o], ft[f][n][kk]; n==8 slot = base weight.
// ---------------------------------------------------------------------------
__global__ __launch_bounds__(256) void k0_prep(
    const float* __restrict__ xb0, const float* __restrict__ xs0,
    const float* __restrict__ yb0, const float* __restrict__ ys0,
    const float* __restrict__ tb0, const float* __restrict__ ts0,
    const float* __restrict__ l1b, const float* __restrict__ l1s,
    const float* __restrict__ l2b, const float* __restrict__ l2s,
    const float* __restrict__ fb0, const float* __restrict__ fs0,
    float* __restrict__ wt, float* __restrict__ lt1, float* __restrict__ lt2,
    float* __restrict__ ft)
{
    const int gid = blockIdx.x * 256 + threadIdx.x;
    if (gid < WT_ELEMS) {
        const int kk = gid & 63;
        int t = gid >> 6;
        const int n = t % 9; t /= 9;
        const int h = t & 127; t >>= 7;
        const int half = t & 1;
        const int m = t >> 1;
        const float* b0 = (m == 0) ? xb0 : (m == 1) ? yb0 : tb0;
        const float* s0 = (m == 0) ? xs0 : (m == 1) ? ys0 : ts0;
        float v = 0.f;
        if (kk < KDIM) {
            const int col = half * 128 + h;
            v = (n < 8) ? s0[(kk * 256 + col) * 8 + n] : b0[kk * 256 + col];
        }
        wt[gid] = v;
    } else if (gid < WT_ELEMS + 2 * LT_ELEMS) {
        int idx = gid - WT_ELEMS;
        const int which = idx >= LT_ELEMS;
        if (which) idx -= LT_ELEMS;
        const float* ls = which ? l2s : l1s;
        const float* lb = which ? l2b : l1b;
        const int o = idx & 127;
        const int t = idx >> 7;
        const int n = t % 9;
        const int h = t / 9;
        const float v = (n < 8) ? ls[(o * 128 + h) * 8 + n] : lb[o * 128 + h];
        (which ? lt2 : lt1)[idx] = v;
    } else {
        const int idx = gid - WT_ELEMS - 2 * LT_ELEMS;  // < FT_ELEMS
        const int kk = idx & 63;
        const int t = idx >> 6;
        const int n = t % 9;
        const int f = t / 9;
        float v = 0.f;
        if (kk < KDIM)
            v = (n < 8) ? fs0[(kk * 384 + f) * 8 + n] : fb0[kk * 384 + f];
        ft[idx] = v;
    }
}

// ---------------------------------------------------------------------------
// KF (1 block, 512 thr): modal-fusion softmax weights.
//   mf = concat of column means; z = kan layer0(mf) via coalesced ft;
//   layer1 + softmax -> wts[3].
// ---------------------------------------------------------------------------
__global__ __launch_bounds__(512) void kf_fusion(
    const float* __restrict__ x, const float* __restrict__ y, const float* __restrict__ tg,
    const float* __restrict__ ft,
    const float* __restrict__ fb1, const float* __restrict__ fs1,
    float* __restrict__ wts)
{
    __shared__ float mfp[768];      // [col][rowhalf]
    __shared__ float fls[4608];     // [f][12]
    __shared__ float zpl[512];      // [fs][kk]
    __shared__ float z[64];
    __shared__ float part3[3 * KDIM];
    const int tid = threadIdx.x;

    // phase A: column means, split 2 row-halves
    for (int idx = tid; idx < 768; idx += 512) {
        const int rh = idx / 384, col = idx % 384;
        const int mm = col >> 7, cc = col & 127;
        const float* in = (mm == 0) ? x : (mm == 1) ? y : tg;
        float s = 0.f;
        for (int r = rh * 96; r < rh * 96 + 96; ++r) s += in[r * HH + cc];
        mfp[col * 2 + rh] = s;
    }
    __syncthreads();
    // phase B: phi of means
    if (tid < 384) {
        const float v = (mfp[tid * 2] + mfp[tid * 2 + 1]) * (1.0f / 192.0f);
        float ph[9];
        kan_phi9(v, ph);
#pragma unroll
        for (int c = 0; c < 9; ++c) fls[tid * 12 + c] = ph[c];
    }
    __syncthreads();
    // phase C: z[k] over f-splits; lane = kk -> ft loads coalesced
    {
        const int kk = tid & 63, fs = tid >> 6;
        float a = 0.f;
        for (int f = fs * 48; f < fs * 48 + 48; ++f) {
            const float* ph = fls + f * 12;              // wave-uniform broadcast
            const float* fw = ft + (size_t)f * 9 * 64 + kk;
#pragma unroll
            for (int n = 0; n < 9; ++n) a += ph[n] * fw[n * 64];
        }
        zpl[fs * 64 + kk] = a;
    }
    __syncthreads();
    if (tid < 64) {
        float s = 0.f;
#pragma unroll
        for (int q = 0; q < 8; ++q) s += zpl[q * 64 + tid];
        z[tid] = s;
    }
    __syncthreads();
    // phase D: layer1 partials (k-parallel), then softmax
    if (tid < KDIM) {
        float ph[9];
        kan_phi9(z[tid], ph);
#pragma unroll
        for (int oo = 0; oo < 3; ++oo) {
            float a = ph[8] * fb1[oo * KDIM + tid];
            const float* sw = fs1 + (oo * KDIM + tid) * 8;
#pragma unroll
            for (int n = 0; n < 8; ++n) a += ph[n] * sw[n];
            part3[oo * KDIM + tid] = a;
        }
    }
    __syncthreads();
    if (tid == 0) {
        float o0 = 0.f, o1 = 0.f, o2 = 0.f;
        for (int k = 0; k < KDIM; ++k) {
            o0 += part3[k]; o1 += part3[KDIM + k]; o2 += part3[2 * KDIM + k];
        }
        const float M  = fmaxf(o0, fmaxf(o1, o2));
        const float e0 = expf(o0 - M), e1 = expf(o1 - M), e2 = expf(o2 - M);
        const float s  = e0 + e1 + e2;
        wts[0] = e0 / s; wts[1] = e1 / s; wts[2] = e2 / s;
    }
}

// ---------------------------------------------------------------------------
// K1 (288 blocks x 512 thr): U[m][i][k], Vt[m][k][j] via concat-split.
// Block = (m, row-pair). Thread = (kk 64) x (half 2) x (h-quarter 4).
// Partial h-sums reduced through LDS. ~9 waves/CU for latency hiding.
// ---------------------------------------------------------------------------
__global__ __launch_bounds__(512) void k1_stage(
    const float* __restrict__ x, const float* __restrict__ y, const float* __restrict__ tg,
    const float* __restrict__ wt,
    float* __restrict__ U, float* __restrict__ Vt)
{
    __shared__ float lds[4096];     // phi 2*128*12 = 3072; part @3072: [hq][half][kk][r]
    const int tid = threadIdx.x;
    const int m  = blockIdx.x / 96;
    const int i0 = (blockIdx.x % 96) * 2;
    const float* in = (m == 0) ? x : (m == 1) ? y : tg;

    if (tid < 256) {
        const int r = tid >> 7, h = tid & 127;
        float ph[9];
        kan_phi9(in[(i0 + r) * HH + h], ph);
#pragma unroll
        for (int c = 0; c < 9; ++c) lds[r * 1536 + h * 12 + c] = ph[c];
    }
    __syncthreads();

    const int kk   = tid & 63;
    const int half = (tid >> 6) & 1;
    const int hq   = tid >> 7;          // 0..3, 32 h each
    const float* wp = wt + (size_t)(((m * 2 + half) * 128 + hq * 32) * 9) * 64 + kk;
    float a0 = 0.f, a1 = 0.f;
    for (int hl = 0; hl < 32; ++hl) {
        const float* f0 = lds + (hq * 32 + hl) * 12;    // wave-uniform -> broadcast
        const float* f1 = f0 + 1536;
        const float* wrow = wp + hl * 576;
#pragma unroll
        for (int n = 0; n < 9; ++n) {
            const float w = wrow[n * 64];               // 256B coalesced, L2-hit
            a0 += f0[n] * w; a1 += f1[n] * w;
        }
    }
    float* part = lds + 3072;
    const int pb = ((hq * 2 + half) * 64 + kk) * 2;
    part[pb + 0] = a0; part[pb + 1] = a1;
    __syncthreads();

    if (tid < 128) {
        const int k2 = tid & 63, hf = tid >> 6;
        if (k2 < KDIM) {
#pragma unroll
            for (int r = 0; r < 2; ++r) {
                float s = 0.f;
#pragma unroll
                for (int q = 0; q < 4; ++q) s += part[((q * 2 + hf) * 64 + k2) * 2 + r];
                if (hf == 0) U[(m * SS + i0 + r) * KDIM + k2] = s;
                else         Vt[(m * KDIM + k2) * SS + i0 + r] = s;
            }
        }
    }
}

// ---------------------------------------------------------------------------
// K2 (576 thr, one block per row i): per-pair layer-1 KAN on z = U[i]+V[j]
// (closed-form uniform cubic B-spline vs zero-padded s1 rows in LDS).
// Thread = (modality m, column j). Fusion + bias, row softmax, att @ target.
// ---------------------------------------------------------------------------
__global__ __launch_bounds__(576) void k2_att(
    const float* __restrict__ tg,
    const float* __restrict__ xb1, const float* __restrict__ xs1,
    const float* __restrict__ yb1, const float* __restrict__ ys1,
    const float* __restrict__ tb1, const float* __restrict__ ts1,
    const float* __restrict__ bias,
    const float* __restrict__ U, const float* __restrict__ Vt,
    const float* __restrict__ wts, float* __restrict__ out)
{
    __shared__ float spad[3 * KDIM * 14];   // s1 rows, 3 zeros padding each side
    __shared__ float Uls[3 * KDIM];
    __shared__ float b1ls[3 * KDIM];
    __shared__ float smpart[576];
    __shared__ float att[SS];
    __shared__ float opart[512];
    __shared__ float red[20];
    __shared__ float wb[4];
    const int tid = threadIdx.x;
    const int i   = blockIdx.x;
    const int lane = tid & 63, wv = tid >> 6;

    for (int idx = tid; idx < 3 * KDIM * 14; idx += 576) {
        const int m = idx / (KDIM * 14);
        const int r = idx % (KDIM * 14);
        const int k = r / 14, c = r % 14;
        const float* s1 = (m == 0) ? xs1 : (m == 1) ? ys1 : ts1;
        spad[idx] = (c >= 3 && c < 11) ? s1[k * 8 + (c - 3)] : 0.f;
    }
    if (tid < 3 * KDIM) {
        const int m = tid / KDIM, k = tid % KDIM;
        const float* b1 = (m == 0) ? xb1 : (m == 1) ? yb1 : tb1;
        b1ls[tid] = b1[k];
        Uls[tid]  = U[(m * SS + i) * KDIM + k];
    }
    if (tid < 3)  wb[tid] = wts[tid];
    if (tid == 3) wb[3] = bias[0];
    __syncthreads();

    {   // phase 1: sm(m, j)
        const int m = tid / 192, j = tid % 192;
        const float* vcol = Vt + m * KDIM * SS + j;
        const float* spm  = spad + m * KDIM * 14;
        const float* Um   = Uls + m * KDIM;
        const float* bm   = b1ls + m * KDIM;
        float sm = 0.f;
        for (int k = 0; k < KDIM; ++k) {
            const float zv  = Um[k] + vcol[k * SS];       // coalesced across j
            const float sig = 1.0f / (1.0f + expf(-zv));
            sm += zv * sig * bm[k];
            float t = (zv + 2.2f) * 2.5f;
            const bool inr = (t >= 0.0f) && (t < 11.0f);
            t = inr ? t : 0.0f;
            const int   c  = (int)t;
            const float u  = t - (float)c;
            const float u2 = u * u, u3 = u2 * u;
            const float wA = (1.0f/6.0f) * (1.0f - 3.0f*u + 3.0f*u2 - u3);
            const float wB = (1.0f/6.0f) * (3.0f*u3 - 6.0f*u2 + 4.0f);
            const float wC = (1.0f/6.0f) * (-3.0f*u3 + 3.0f*u2 + 3.0f*u + 1.0f);
            const float wD = (1.0f/6.0f) * u3;
            const float* sp = spm + k * 14 + c;           // sp[0] == s1[c-3] (padded)
            const float spl = wA*sp[0] + wB*sp[1] + wC*sp[2] + wD*sp[3];
            sm += inr ? spl : 0.0f;
        }
        smpart[tid] = wb[m] * sm;
    }
    __syncthreads();

    // phase 2: fuse + row softmax over 192 columns (threads 0..191)
    float f = 0.f;
    if (tid < SS) f = wb[3] + smpart[tid] + smpart[tid + 192] + smpart[tid + 384];
    float mx = f;
#pragma unroll
    for (int o = 32; o > 0; o >>= 1) mx = fmaxf(mx, __shfl_xor(mx, o));
    if (lane == 0) red[wv] = mx;
    __syncthreads();
    mx = fmaxf(red[0], fmaxf(red[1], red[2]));
    const float p = (tid < SS) ? expf(f - mx) : 0.f;
    float sum = p;
#pragma unroll
    for (int o = 32; o > 0; o >>= 1) sum += __shfl_xor(sum, o);
    if (lane == 0) red[10 + wv] = sum;
    __syncthreads();
    sum = red[10] + red[11] + red[12];
    if (tid < SS) att[tid] = p / sum;
    __syncthreads();

    // phase 3: out[i][:] = att @ target, 4 row-chunks of 48 in parallel
    if (tid < 512) {
        const int col = tid & 127, ch = tid >> 7;
        float acc = 0.f;
        for (int jj = ch * 48; jj < ch * 48 + 48; ++jj)
            acc += att[jj] * tg[jj * HH + col];
        opart[tid] = acc;
    }
    __syncthreads();
    if (tid < HH)
        out[i * HH + tid] = opart[tid] + opart[tid + 128] + opart[tid + 256] + opart[tid + 384];
}

// ---------------------------------------------------------------------------
// K3/K4: y = relu(kan_linear(in, lt)), lt pre-transposed [h][n][o].
// 1 row/block, 512 threads: o = tid&127 (lane-coalesced), h-quarter = tid>>7.
// ---------------------------------------------------------------------------
__global__ __launch_bounds__(512) void k3_kanlin_relu(
    const float* __restrict__ in, const float* __restrict__ lt,
    float* __restrict__ out)
{
    __shared__ float lds[2048];            // phi [128][12] = 1536; part @1536 [4][128]
    const int tid = threadIdx.x;
    const int i   = blockIdx.x;
    if (tid < 128) {
        float ph[9];
        kan_phi9(in[i * HH + tid], ph);
#pragma unroll
        for (int c = 0; c < 9; ++c) lds[tid * 12 + c] = ph[c];
    }
    __syncthreads();
    const int o  = tid & 127;
    const int hq = tid >> 7;
    const float* wp = lt + (size_t)((hq * 32) * 9) * 128 + o;
    float a = 0.f;
    for (int hl = 0; hl < 32; ++hl) {
        const float* f0 = lds + (hq * 32 + hl) * 12;      // wave-uniform broadcast
        const float* wrow = wp + hl * 1152;
#pragma unroll
        for (int n = 0; n < 9; ++n) a += f0[n] * wrow[n * 128];
    }
    float* part = lds + 1536;
    part[hq * 128 + o] = a;
    __syncthreads();
    if (tid < 128) {
        const float s = part[tid] + part[128 + tid] + part[256 + tid] + part[384 + tid];
        out[i * HH + tid] = fmaxf(s, 0.f);
    }
}

// ---------------------------------------------------------------------------
extern "C" void kernel_launch(void* const* d_in, const int* in_sizes, int n_in,
                              void* d_out, int out_size, void* d_ws, size_t ws_size,
                              hipStream_t stream) {
    const float* x    = (const float*)d_in[0];
    const float* y    = (const float*)d_in[1];
    const float* tg   = (const float*)d_in[2];
    const float* bias = (const float*)d_in[3];
    const float* xb0  = (const float*)d_in[4];
    const float* xs0  = (const float*)d_in[5];
    const float* xb1  = (const float*)d_in[6];
    const float* xs1  = (const float*)d_in[7];
    const float* yb0  = (const float*)d_in[8];
    const float* ys0  = (const float*)d_in[9];
    const float* yb1  = (const float*)d_in[10];
    const float* ys1  = (const float*)d_in[11];
    const float* tb0  = (const float*)d_in[12];
    const float* ts0  = (const float*)d_in[13];
    const float* tb1  = (const float*)d_in[14];
    const float* ts1  = (const float*)d_in[15];
    const float* fb0  = (const float*)d_in[16];
    const float* fs0  = (const float*)d_in[17];
    const float* fb1  = (const float*)d_in[18];
    const float* fs1  = (const float*)d_in[19];
    const float* l1b  = (const float*)d_in[20];
    const float* l1s  = (const float*)d_in[21];
    const float* l2b  = (const float*)d_in[22];
    const float* l2s  = (const float*)d_in[23];

    float* ws   = (float*)d_ws;
    float* wt   = ws;                       // 442368
    float* lt1  = wt + WT_ELEMS;            // 147456
    float* lt2  = lt1 + LT_ELEMS;           // 147456
    float* ft   = lt2 + LT_ELEMS;           // 221184
    float* U    = ft + FT_ELEMS;            // 28800
    float* Vt   = U + 28800;                // 28800
    float* wts  = Vt + 28800;               // 64
    float* tgt  = wts + 64;                 // 24576
    float* y1   = tgt + 24576;              // 24576  (total ~4.3 MB)
    float* outp = (float*)d_out;

    k0_prep<<<3744, 256, 0, stream>>>(xb0, xs0, yb0, ys0, tb0, ts0,
                                      l1b, l1s, l2b, l2s, fb0, fs0,
                                      wt, lt1, lt2, ft);
    kf_fusion<<<1, 512, 0, stream>>>(x, y, tg, ft, fb1, fs1, wts);
    k1_stage<<<288, 512, 0, stream>>>(x, y, tg, wt, U, Vt);
    k2_att<<<SS, 576, 0, stream>>>(tg, xb1, xs1, yb1, ys1, tb1, ts1, bias,
                                   U, Vt, wts, tgt);
    k3_kanlin_relu<<<192, 512, 0, stream>>>(tgt, lt1, y1);
    k3_kanlin_relu<<<192, 512, 0, stream>>>(y1, lt2, outp);
}

// Round 14
// 162.602 us; speedup vs baseline: 1.2848x; 1.0717x over previous
//
#include <hip/hip_runtime.h>
#include <math.h>

#define SS 192
#define HH 128
#define KDIM 50

#define WT_ELEMS   442368                 // 3*2*128*9*64   wt[m][half][h][n][kk] (kk-pad unwritten)
#define LT_ELEMS   147456                 // 128*9*128      lt[h][n][o]
#define FT_ELEMS   221184                 // 384*9*64       ft[f][n][kk] (kk-pad unwritten)

#define W_SRC      345600                 // 3*50*256*9 written elements of wt
#define L_SRC      147456                 // 128*128*9 per lt
#define F_SRC      172800                 // 50*384*9 written elements of ft

// ---------------------------------------------------------------------------
// Cox-de Boor features: o[0..7] = cubic B-spline bases (12 uniform knots,
// spacing 0.4 on [-2.2,2.2]), o[8] = silu(x). Matches reference recursion.
// ---------------------------------------------------------------------------
__device__ __forceinline__ void kan_phi9(float x, float* o) {
    float g[12];
#pragma unroll
    for (int i = 0; i < 12; ++i) g[i] = (float)(i - 3) * 0.4f - 1.0f;
    float b[11];
#pragma unroll
    for (int i = 0; i < 11; ++i) b[i] = (x >= g[i] && x < g[i + 1]) ? 1.0f : 0.0f;
#pragma unroll
    for (int p = 1; p <= 3; ++p) {
#pragma unroll
        for (int i = 0; i + p < 11; ++i) {
            float l = (x - g[i]) * (1.0f / (g[i + p] - g[i]));
            float r = (g[i + p + 1] - x) * (1.0f / (g[i + p + 1] - g[i + 1]));
            b[i] = l * b[i] + r * b[i + 1];   // ascending in-place: b[i+1] still old
        }
    }
#pragma unroll
    for (int i = 0; i < 8; ++i) o[i] = b[i];
    o[8] = x / (1.0f + __expf(-x));
}

// ---------------------------------------------------------------------------
// K0: weight re-layouts, READ-coalesced (gid linear in source; scatter on the
// write side). kk in [50,64) pad slots are never consumed -> left unwritten.
// ---------------------------------------------------------------------------
__global__ __launch_bounds__(256) void k0_prep(
    const float* __restrict__ xb0, const float* __restrict__ xs0,
    const float* __restrict__ yb0, const float* __restrict__ ys0,
    const float* __restrict__ tb0, const float* __restrict__ ts0,
    const float* __restrict__ l1b, const float* __restrict__ l1s,
    const float* __restrict__ l2b, const float* __restrict__ l2s,
    const float* __restrict__ fb0, const float* __restrict__ fs0,
    float* __restrict__ wt, float* __restrict__ lt1, float* __restrict__ lt2,
    float* __restrict__ ft)
{
    const int gid = blockIdx.x * 256 + threadIdx.x;
    if (gid < W_SRC) {
        const int n = gid % 9;
        int t = gid / 9;
        const int col = t & 255; t >>= 8;
        const int kk = t % 50;
        const int m  = t / 50;
        const float* b0 = (m == 0) ? xb0 : (m == 1) ? yb0 : tb0;
        const float* s0 = (m == 0) ? xs0 : (m == 1) ? ys0 : ts0;
        const float v = (n < 8) ? s0[(kk * 256 + col) * 8 + n] : b0[kk * 256 + col];
        wt[(((m * 2 + (col >> 7)) * 128 + (col & 127)) * 9 + n) * 64 + kk] = v;
    } else if (gid < W_SRC + 2 * L_SRC) {
        int idx = gid - W_SRC;
        const int which = idx >= L_SRC;
        if (which) idx -= L_SRC;
        const float* ls = which ? l2s : l1s;
        const float* lb = which ? l2b : l1b;
        const int n = idx % 9;
        const int t = idx / 9;
        const int h = t & 127, o = t >> 7;
        const float v = (n < 8) ? ls[(o * 128 + h) * 8 + n] : lb[o * 128 + h];
        (which ? lt2 : lt1)[(h * 9 + n) * 128 + o] = v;
    } else if (gid < W_SRC + 2 * L_SRC + F_SRC) {
        const int idx = gid - W_SRC - 2 * L_SRC;
        const int n = idx % 9;
        const int t = idx / 9;
        const int f = t % 384, kk = t / 384;
        const float v = (n < 8) ? fs0[(kk * 384 + f) * 8 + n] : fb0[kk * 384 + f];
        ft[(f * 9 + n) * 64 + kk] = v;
    }
}

// ---------------------------------------------------------------------------
// KA (289 blocks x 512 thr):
//   blocks 0..287: U[m][i][k], Vt[m][k][j] via concat-split of pair-KAN L0.
//     Block = (m, row-pair). Thread = (kk 64) x (half 2) x (h-quarter 4).
//   block 288: modal-fusion softmax weights wts[3].
// ---------------------------------------------------------------------------
__global__ __launch_bounds__(512) void ka_stage(
    const float* __restrict__ x, const float* __restrict__ y, const float* __restrict__ tg,
    const float* __restrict__ wt, const float* __restrict__ ft,
    const float* __restrict__ fb1, const float* __restrict__ fs1,
    float* __restrict__ U, float* __restrict__ Vt, float* __restrict__ wts)
{
    __shared__ float lds[6144];
    const int tid = threadIdx.x;
    const int bid = blockIdx.x;

    if (bid < 288) {
        const int m  = bid / 96;
        const int i0 = (bid % 96) * 2;
        const float* in = (m == 0) ? x : (m == 1) ? y : tg;

        if (tid < 256) {
            const int r = tid >> 7, h = tid & 127;
            float ph[9];
            kan_phi9(in[(i0 + r) * HH + h], ph);
#pragma unroll
            for (int c = 0; c < 9; ++c) lds[r * 1536 + h * 12 + c] = ph[c];
        }
        __syncthreads();

        const int kk   = tid & 63;
        const int half = (tid >> 6) & 1;
        const int hq   = tid >> 7;          // 0..3, 32 h each
        const float* wp = wt + (size_t)(((m * 2 + half) * 128 + hq * 32) * 9) * 64 + kk;
        float a0 = 0.f, a1 = 0.f;
        for (int hl = 0; hl < 32; ++hl) {
            const float* f0 = lds + (hq * 32 + hl) * 12;    // wave-uniform broadcast
            const float* f1 = f0 + 1536;
            const float* wrow = wp + hl * 576;
#pragma unroll
            for (int n = 0; n < 9; ++n) {
                const float w = wrow[n * 64];               // 256B coalesced, L2-hit
                a0 += f0[n] * w; a1 += f1[n] * w;
            }
        }
        float* part = lds + 3072;
        const int pb = ((hq * 2 + half) * 64 + kk) * 2;
        part[pb + 0] = a0; part[pb + 1] = a1;
        __syncthreads();

        if (tid < 128) {
            const int k2 = tid & 63, hf = tid >> 6;
            if (k2 < KDIM) {
#pragma unroll
                for (int r = 0; r < 2; ++r) {
                    float s = 0.f;
#pragma unroll
                    for (int q = 0; q < 4; ++q) s += part[((q * 2 + hf) * 64 + k2) * 2 + r];
                    if (hf == 0) U[(m * SS + i0 + r) * KDIM + k2] = s;
                    else         Vt[(m * KDIM + k2) * SS + i0 + r] = s;
                }
            }
        }
    } else {
        // ---- modal fusion weights ----
        float* mfp   = lds;           // 768 [col][rowhalf]
        float* fls   = lds + 768;     // 4608 [f][12]
        float* zpl   = lds + 5376;    // 512 [fs][kk]
        float* z     = lds + 5888;    // 64
        float* part3 = lds + 5952;    // 150

        for (int idx = tid; idx < 768; idx += 512) {
            const int rh = idx / 384, col = idx % 384;
            const int mm = col >> 7, cc = col & 127;
            const float* in = (mm == 0) ? x : (mm == 1) ? y : tg;
            float s = 0.f;
            for (int r = rh * 96; r < rh * 96 + 96; ++r) s += in[r * HH + cc];
            mfp[col * 2 + rh] = s;
        }
        __syncthreads();
        if (tid < 384) {
            const float v = (mfp[tid * 2] + mfp[tid * 2 + 1]) * (1.0f / 192.0f);
            float ph[9];
            kan_phi9(v, ph);
#pragma unroll
            for (int c = 0; c < 9; ++c) fls[tid * 12 + c] = ph[c];
        }
        __syncthreads();
        {   // z[k] over f-splits; lane = kk -> coalesced ft loads
            const int kk = tid & 63, fs = tid >> 6;
            float a = 0.f;
            for (int f = fs * 48; f < fs * 48 + 48; ++f) {
                const float* ph = fls + f * 12;
                const float* fw = ft + (size_t)f * 9 * 64 + kk;
#pragma unroll
                for (int n = 0; n < 9; ++n) a += ph[n] * fw[n * 64];
            }
            zpl[fs * 64 + kk] = a;
        }
        __syncthreads();
        if (tid < 64) {
            float s = 0.f;
#pragma unroll
            for (int q = 0; q < 8; ++q) s += zpl[q * 64 + tid];
            z[tid] = s;
        }
        __syncthreads();
        if (tid < KDIM) {
            float ph[9];
            kan_phi9(z[tid], ph);
#pragma unroll
            for (int oo = 0; oo < 3; ++oo) {
                float a = ph[8] * fb1[oo * KDIM + tid];
                const float* sw = fs1 + (oo * KDIM + tid) * 8;
#pragma unroll
                for (int n = 0; n < 8; ++n) a += ph[n] * sw[n];
                part3[oo * KDIM + tid] = a;
            }
        }
        __syncthreads();
        if (tid == 0) {
            float o0 = 0.f, o1 = 0.f, o2 = 0.f;
            for (int k = 0; k < KDIM; ++k) {
                o0 += part3[k]; o1 += part3[KDIM + k]; o2 += part3[2 * KDIM + k];
            }
            const float M  = fmaxf(o0, fmaxf(o1, o2));
            const float e0 = __expf(o0 - M), e1 = __expf(o1 - M), e2 = __expf(o2 - M);
            const float s  = e0 + e1 + e2;
            wts[0] = e0 / s; wts[1] = e1 / s; wts[2] = e2 / s;
        }
    }
}

// ---------------------------------------------------------------------------
// KB (192 blocks x 576 thr, one block per row i) — fully fused tail:
//   per-pair layer-1 KAN on z=U[i]+V[j] (closed-form cubic spline), fusion +
//   bias, row softmax, att @ target, then BOTH output-KAN layers (row-local):
//   relu(kanlin(relu(kanlin(tgt_row, lt1)), lt2)) -> out row.
// ---------------------------------------------------------------------------
__global__ __launch_bounds__(576) void kb_row(
    const float* __restrict__ tg,
    const float* __restrict__ xb1, const float* __restrict__ xs1,
    const float* __restrict__ yb1, const float* __restrict__ ys1,
    const float* __restrict__ tb1, const float* __restrict__ ts1,
    const float* __restrict__ bias,
    const float* __restrict__ U, const float* __restrict__ Vt,
    const float* __restrict__ wts,
    const float* __restrict__ lt1, const float* __restrict__ lt2,
    float* __restrict__ out)
{
    __shared__ float spad[3 * KDIM * 14];   // s1 rows, 3 zeros pad each side
    __shared__ float Uls[3 * KDIM];
    __shared__ float b1ls[3 * KDIM];
    __shared__ float smpart[576];
    __shared__ float att[SS];
    __shared__ float opart[512];
    __shared__ float rowbuf[HH];
    __shared__ float phi[1536];             // [128][12]
    __shared__ float part[512];
    __shared__ float red[20];
    __shared__ float wb[4];
    const int tid = threadIdx.x;
    const int i   = blockIdx.x;
    const int lane = tid & 63, wv = tid >> 6;

    for (int idx = tid; idx < 3 * KDIM * 14; idx += 576) {
        const int m = idx / (KDIM * 14);
        const int r = idx % (KDIM * 14);
        const int k = r / 14, c = r % 14;
        const float* s1 = (m == 0) ? xs1 : (m == 1) ? ys1 : ts1;
        spad[idx] = (c >= 3 && c < 11) ? s1[k * 8 + (c - 3)] : 0.f;
    }
    if (tid < 3 * KDIM) {
        const int m = tid / KDIM, k = tid % KDIM;
        const float* b1 = (m == 0) ? xb1 : (m == 1) ? yb1 : tb1;
        b1ls[tid] = b1[k];
        Uls[tid]  = U[(m * SS + i) * KDIM + k];
    }
    if (tid < 3)  wb[tid] = wts[tid];
    if (tid == 3) wb[3] = bias[0];
    __syncthreads();

    {   // phase 1: sm(m, j)
        const int m = tid / 192, j = tid % 192;
        const float* vcol = Vt + m * KDIM * SS + j;
        const float* spm  = spad + m * KDIM * 14;
        const float* Um   = Uls + m * KDIM;
        const float* bm   = b1ls + m * KDIM;
        float sm = 0.f;
        for (int k = 0; k < KDIM; ++k) {
            const float zv  = Um[k] + vcol[k * SS];       // coalesced across j
            const float sig = 1.0f / (1.0f + __expf(-zv));
            sm += zv * sig * bm[k];
            float t = (zv + 2.2f) * 2.5f;
            const bool inr = (t >= 0.0f) && (t < 11.0f);
            t = inr ? t : 0.0f;
            const int   c  = (int)t;
            const float u  = t - (float)c;
            const float u2 = u * u, u3 = u2 * u;
            const float wA = (1.0f/6.0f) * (1.0f - 3.0f*u + 3.0f*u2 - u3);
            const float wB = (1.0f/6.0f) * (3.0f*u3 - 6.0f*u2 + 4.0f);
            const float wC = (1.0f/6.0f) * (-3.0f*u3 + 3.0f*u2 + 3.0f*u + 1.0f);
            const float wD = (1.0f/6.0f) * u3;
            const float* sp = spm + k * 14 + c;           // sp[0] == s1[c-3] (padded)
            const float spl = wA*sp[0] + wB*sp[1] + wC*sp[2] + wD*sp[3];
            sm += inr ? spl : 0.0f;
        }
        smpart[tid] = wb[m] * sm;
    }
    __syncthreads();

    // phase 2: fuse + row softmax over 192 columns (threads 0..191)
    float f = 0.f;
    if (tid < SS) f = wb[3] + smpart[tid] + smpart[tid + 192] + smpart[tid + 384];
    float mx = f;
#pragma unroll
    for (int o = 32; o > 0; o >>= 1) mx = fmaxf(mx, __shfl_xor(mx, o));
    if (lane == 0) red[wv] = mx;
    __syncthreads();
    mx = fmaxf(red[0], fmaxf(red[1], red[2]));
    const float p = (tid < SS) ? __expf(f - mx) : 0.f;
    float sum = p;
#pragma unroll
    for (int o = 32; o > 0; o >>= 1) sum += __shfl_xor(sum, o);
    if (lane == 0) red[10 + wv] = sum;
    __syncthreads();
    sum = red[10] + red[11] + red[12];
    if (tid < SS) att[tid] = p / sum;
    __syncthreads();

    // phase 3: tgt_row = att @ target (4 row-chunks of 48)
    if (tid < 512) {
        const int col = tid & 127, ch = tid >> 7;
        float acc = 0.f;
        for (int jj = ch * 48; jj < ch * 48 + 48; ++jj)
            acc += att[jj] * tg[jj * HH + col];
        opart[tid] = acc;
    }
    __syncthreads();
    if (tid < HH)
        rowbuf[tid] = opart[tid] + opart[tid + 128] + opart[tid + 256] + opart[tid + 384];
    __syncthreads();

    // phases 4-7: two fused kan_linear+relu layers, row-local
#pragma unroll
    for (int layer = 0; layer < 2; ++layer) {
        const float* lt = (layer == 0) ? lt1 : lt2;
        if (tid < HH) {
            float ph[9];
            kan_phi9(rowbuf[tid], ph);
#pragma unroll
            for (int c = 0; c < 9; ++c) phi[tid * 12 + c] = ph[c];
        }
        __syncthreads();
        if (tid < 512) {
            const int o  = tid & 127;
            const int hq = tid >> 7;
            const float* wp = lt + (size_t)((hq * 32) * 9) * 128 + o;
            float a = 0.f;
            for (int hl = 0; hl < 32; ++hl) {
                const float* f0 = phi + (hq * 32 + hl) * 12;   // wave-uniform broadcast
                const float* wrow = wp + hl * 1152;
#pragma unroll
                for (int n = 0; n < 9; ++n) a += f0[n] * wrow[n * 128];
            }
            part[hq * 128 + o] = a;
        }
        __syncthreads();
        if (tid < HH) {
            const float s = part[tid] + part[128 + tid] + part[256 + tid] + part[384 + tid];
            rowbuf[tid] = fmaxf(s, 0.f);
        }
        __syncthreads();
    }
    if (tid < HH) out[i * HH + tid] = rowbuf[tid];
}

// ---------------------------------------------------------------------------
extern "C" void kernel_launch(void* const* d_in, const int* in_sizes, int n_in,
                              void* d_out, int out_size, void* d_ws, size_t ws_size,
                              hipStream_t stream) {
    const float* x    = (const float*)d_in[0];
    const float* y    = (const float*)d_in[1];
    const float* tg   = (const float*)d_in[2];
    const float* bias = (const float*)d_in[3];
    const float* xb0  = (const float*)d_in[4];
    const float* xs0  = (const float*)d_in[5];
    const float* xb1  = (const float*)d_in[6];
    const float* xs1  = (const float*)d_in[7];
    const float* yb0  = (const float*)d_in[8];
    const float* ys0  = (const float*)d_in[9];
    const float* yb1  = (const float*)d_in[10];
    const float* ys1  = (const float*)d_in[11];
    const float* tb0  = (const float*)d_in[12];
    const float* ts0  = (const float*)d_in[13];
    const float* tb1  = (const float*)d_in[14];
    const float* ts1  = (const float*)d_in[15];
    const float* fb0  = (const float*)d_in[16];
    const float* fs0  = (const float*)d_in[17];
    const float* fb1  = (const float*)d_in[18];
    const float* fs1  = (const float*)d_in[19];
    const float* l1b  = (const float*)d_in[20];
    const float* l1s  = (const float*)d_in[21];
    const float* l2b  = (const float*)d_in[22];
    const float* l2s  = (const float*)d_in[23];

    float* ws   = (float*)d_ws;
    float* wt   = ws;                       // 442368
    float* lt1  = wt + WT_ELEMS;            // 147456
    float* lt2  = lt1 + LT_ELEMS;           // 147456
    float* ft   = lt2 + LT_ELEMS;           // 221184
    float* U    = ft + FT_ELEMS;            // 28800
    float* Vt   = U + 28800;                // 28800
    float* wts  = Vt + 28800;               // 64    (total ~3.7 MB)
    float* outp = (float*)d_out;

    k0_prep<<<3177, 256, 0, stream>>>(xb0, xs0, yb0, ys0, tb0, ts0,
                                      l1b, l1s, l2b, l2s, fb0, fs0,
                                      wt, lt1, lt2, ft);
    ka_stage<<<289, 512, 0, stream>>>(x, y, tg, wt, ft, fb1, fs1, U, Vt, wts);
    kb_row<<<SS, 576, 0, stream>>>(tg, xb1, xs1, yb1, ys1, tb1, ts1, bias,
                                   U, Vt, wts, lt1, lt2, outp);
}